// Round 1
// baseline (124.346 us; speedup 1.0000x reference)
//
#include <hip/hip_runtime.h>

// Problem: B=16, C=64, H=256, W=256, K=2 non-overlapping vector max-pool.
// p = sqrt(u^2+v^2); per 2x2 window pick the (u,v) at argmax(p) (first max).
// sqrt is monotonic -> compare squared magnitudes; strict > keeps first-max.
//
// Layout: inputs [B,C,256,256] f32; outputs u_out,v_out each [B,C,128,128] f32,
// concatenated flat in d_out.
//
// One thread handles 2 adjacent output pixels: 4x float4 loads (16B/lane,
// fully coalesced), 2x float2 stores per output tensor.

#define BC (16 * 64)          // fused batch*channel
#define W_IN 256
#define H_IN 256
#define W_OUT 128
#define H_OUT 128
#define PAIRS_PER_ROW (W_OUT / 2)   // 64
#define OUT_PLANE (W_OUT * H_OUT)   // 16384
#define IN_PLANE (W_IN * H_IN)      // 65536
#define N_THREADS (BC * H_OUT * PAIRS_PER_ROW)  // 8,388,608

__global__ __launch_bounds__(256) void vector_maxpool_kernel(
    const float* __restrict__ u, const float* __restrict__ v,
    float* __restrict__ uo, float* __restrict__ vo) {
  int tid = blockIdx.x * blockDim.x + threadIdx.x;

  int wp = tid & (PAIRS_PER_ROW - 1);        // pair index within row [0,64)
  int ho = (tid >> 6) & (H_OUT - 1);         // output row [0,128)
  int bc = tid >> 13;                        // fused b*c [0,1024)

  size_t in_base = (size_t)bc * IN_PLANE + (size_t)(2 * ho) * W_IN + (size_t)wp * 4;

  const float4 u0 = *(const float4*)(u + in_base);          // top row, 4 cols
  const float4 u1 = *(const float4*)(u + in_base + W_IN);   // bottom row
  const float4 v0 = *(const float4*)(v + in_base);
  const float4 v1 = *(const float4*)(v + in_base + W_IN);

  float2 uout, vout;

  // Window A: cols {4wp, 4wp+1}. Candidate order TL, TR, BL, BR (first-max).
  {
    float m0 = u0.x * u0.x + v0.x * v0.x;
    float m1 = u0.y * u0.y + v0.y * v0.y;
    float m2 = u1.x * u1.x + v1.x * v1.x;
    float m3 = u1.y * u1.y + v1.y * v1.y;
    float bm = m0, bu = u0.x, bv = v0.x;
    if (m1 > bm) { bm = m1; bu = u0.y; bv = v0.y; }
    if (m2 > bm) { bm = m2; bu = u1.x; bv = v1.x; }
    if (m3 > bm) { bm = m3; bu = u1.y; bv = v1.y; }
    uout.x = bu; vout.x = bv;
  }
  // Window B: cols {4wp+2, 4wp+3}.
  {
    float m0 = u0.z * u0.z + v0.z * v0.z;
    float m1 = u0.w * u0.w + v0.w * v0.w;
    float m2 = u1.z * u1.z + v1.z * v1.z;
    float m3 = u1.w * u1.w + v1.w * v1.w;
    float bm = m0, bu = u0.z, bv = v0.z;
    if (m1 > bm) { bm = m1; bu = u0.w; bv = v0.w; }
    if (m2 > bm) { bm = m2; bu = u1.z; bv = v1.z; }
    if (m3 > bm) { bm = m3; bu = u1.w; bv = v1.w; }
    uout.y = bu; vout.y = bv;
  }

  size_t out_idx = (size_t)bc * OUT_PLANE + (size_t)ho * W_OUT + (size_t)wp * 2;
  *(float2*)(uo + out_idx) = uout;
  *(float2*)(vo + out_idx) = vout;
}

extern "C" void kernel_launch(void* const* d_in, const int* in_sizes, int n_in,
                              void* d_out, int out_size, void* d_ws, size_t ws_size,
                              hipStream_t stream) {
  const float* u = (const float*)d_in[0];
  const float* v = (const float*)d_in[1];
  float* uo = (float*)d_out;
  float* vo = uo + (size_t)BC * OUT_PLANE;  // v_out follows u_out flat

  int threads = 256;
  int blocks = N_THREADS / threads;  // 32768
  vector_maxpool_kernel<<<blocks, threads, 0, stream>>>(u, v, uo, vo);
}